// Round 3
// baseline (269.389 us; speedup 1.0000x reference)
//
#include <hip/hip_runtime.h>

// RNN: h_{t+1} = tanh(x_t @ W_ih^T + b_ih + b_hh + h_t @ W_hh^T), out = h_T @ fc_w^T + fc_b
// B=8192, T=512, IN=8, H=16.
//
// Round 3: recurrence h-exchange moved from LDS round-trip (≈200 cyc/step serial
// latency, measured 99 µs) to DPP row_ror cross-lane rotates (pure VALU).
// 16 lanes per batch element == one DPP row; lane j owns h_j and the permuted
// W_hh row wperm[r] = W_hh[j][(j-r)&15], so  s_j = Σ_r wperm[r]*ror_r(h).
// x staged to LDS in coalesced 32-timestep tiles (off the critical path).

#define RNN_B   8192
#define RNN_T   512
#define RNN_IN  8
#define RNN_H   16
#define TC      32                 // timesteps per x tile
#define NB      16                 // batch elements per block
#define XSTRIDE 264                // padded floats per xs row

// row_ror:R within 16-lane DPP row: lane i receives h from lane (i-R) & 15.
template<int R>
__device__ __forceinline__ float ror16(float v) {
    return __int_as_float(__builtin_amdgcn_update_dpp(
        0, __float_as_int(v), 0x120 + R, 0xF, 0xF, false));
}

__global__ __launch_bounds__(256, 2) void rnn_fused_kernel(
    const float* __restrict__ x,     // [B, T, IN]
    const float* __restrict__ W_ih,  // [H, IN]
    const float* __restrict__ W_hh,  // [H, H]
    const float* __restrict__ b_ih,  // [H]
    const float* __restrict__ b_hh,  // [H]
    const float* __restrict__ fc_w,  // [1, H]
    const float* __restrict__ fc_b,  // [1]
    float* __restrict__ out)         // [B, 1]
{
    __shared__ float xs[NB * XSTRIDE];   // x tile: 16 rows x (32 t x 8 in), padded

    const int tid = (int)threadIdx.x;
    const int j   = tid & 15;            // hidden unit (lane within DPP row)
    const int g   = tid >> 4;            // batch element within block
    const int b0  = (int)blockIdx.x * NB;
    const int b   = b0 + g;

    // --- per-lane weights ---
    // wperm[r] = W_hh[j][(j - r) & 15]  (matches row_ror data movement)
    float wperm[RNN_H];
#pragma unroll
    for (int r = 0; r < RNN_H; ++r) {
        wperm[r] = W_hh[j * RNN_H + ((j - r) & 15)];
    }
    float wih[RNN_IN];
#pragma unroll
    for (int i = 0; i < RNN_IN; i += 4) {
        float4 w = *(const float4*)(W_ih + j * RNN_IN + i);
        wih[i] = w.x; wih[i+1] = w.y; wih[i+2] = w.z; wih[i+3] = w.w;
    }
    const float bias = b_ih[j] + b_hh[j];

    float h = 0.0f;                      // h_j lives in-register, per lane

    for (int t0 = 0; t0 < RNN_T; t0 += TC) {
        __syncthreads();   // previous tile's xs reads complete
        // --- stage x tile: 16 rows x 256 floats = 1024 float4; 4 per thread ---
#pragma unroll
        for (int p = 0; p < 4; ++p) {
            int idx = tid + p * 256;
            int row = idx >> 6;          // 0..15
            int off = idx & 63;          // float4 index within row
            float4 v = *(const float4*)(x + ((size_t)(b0 + row) * RNN_T + t0) * RNN_IN + off * 4);
            *(float4*)(xs + row * XSTRIDE + off * 4) = v;
        }
        __syncthreads();

#pragma unroll 8
        for (int tt = 0; tt < TC; ++tt) {
            const float* xp = xs + g * XSTRIDE + tt * RNN_IN;
            const float4 xa = *(const float4*)(xp);
            const float4 xb = *(const float4*)(xp + 4);

            // input projection: 2 chains
            float a0 = fmaf(wih[0], xa.x, bias);
            a0 = fmaf(wih[1], xa.y, a0);
            a0 = fmaf(wih[2], xa.z, a0);
            a0 = fmaf(wih[3], xa.w, a0);

            float a1 = wih[4] * xb.x;
            a1 = fmaf(wih[5], xb.y, a1);
            a1 = fmaf(wih[6], xb.z, a1);
            a1 = fmaf(wih[7], xb.w, a1);

            // recurrence: 16 terms via DPP rotates, 4 accumulator chains
            float a2 = wperm[0] * h;
            float a3 = wperm[1] * ror16<1>(h);
            a0 = fmaf(wperm[2],  ror16<2>(h),  a0);
            a1 = fmaf(wperm[3],  ror16<3>(h),  a1);
            a2 = fmaf(wperm[4],  ror16<4>(h),  a2);
            a3 = fmaf(wperm[5],  ror16<5>(h),  a3);
            a0 = fmaf(wperm[6],  ror16<6>(h),  a0);
            a1 = fmaf(wperm[7],  ror16<7>(h),  a1);
            a2 = fmaf(wperm[8],  ror16<8>(h),  a2);
            a3 = fmaf(wperm[9],  ror16<9>(h),  a3);
            a0 = fmaf(wperm[10], ror16<10>(h), a0);
            a1 = fmaf(wperm[11], ror16<11>(h), a1);
            a2 = fmaf(wperm[12], ror16<12>(h), a2);
            a3 = fmaf(wperm[13], ror16<13>(h), a3);
            a0 = fmaf(wperm[14], ror16<14>(h), a0);
            a1 = fmaf(wperm[15], ror16<15>(h), a1);

            const float s = (a0 + a1) + (a2 + a3);

            // tanh(s) = 1 - 2/(exp(2s)+1); saturates correctly at +/-inf
            const float e = __expf(s + s);
            const float r = __builtin_amdgcn_rcpf(e + 1.0f);
            h = fmaf(-2.0f, r, 1.0f);
        }
    }

    // --- epilogue: out[b] = sum_j fc_w[j] * h_j + fc_b ---
    float v = h * fc_w[j];
    v += __shfl_xor(v, 1);
    v += __shfl_xor(v, 2);
    v += __shfl_xor(v, 4);
    v += __shfl_xor(v, 8);
    if (j == 0) out[b] = v + fc_b[0];
}

extern "C" void kernel_launch(void* const* d_in, const int* in_sizes, int n_in,
                              void* d_out, int out_size, void* d_ws, size_t ws_size,
                              hipStream_t stream)
{
    const float* x    = (const float*)d_in[0];
    const float* W_ih = (const float*)d_in[1];
    const float* W_hh = (const float*)d_in[2];
    const float* b_ih = (const float*)d_in[3];
    const float* b_hh = (const float*)d_in[4];
    const float* fc_w = (const float*)d_in[5];
    const float* fc_b = (const float*)d_in[6];
    float* out = (float*)d_out;

    dim3 grid(RNN_B / NB);   // 512 blocks
    dim3 block(256);
    rnn_fused_kernel<<<grid, block, 0, stream>>>(x, W_ih, W_hh, b_ih, b_hh, fc_w, fc_b, out);
}